// Round 7
// baseline (1443.106 us; speedup 1.0000x reference)
//
#include <hip/hip_runtime.h>

// ---- problem constants ----
#define NE 16
#define DD 2048
#define HH 1408
#define HSH 2816
#define TOPK 6
#define TT 4096

typedef __bf16 bf16x8 __attribute__((ext_vector_type(8)));
typedef __bf16 bf16x4 __attribute__((ext_vector_type(4)));
typedef float f32x4 __attribute__((ext_vector_type(4)));

typedef const __attribute__((address_space(1))) void gvoid_t;
typedef __attribute__((address_space(3))) void lvoid_t;

__device__ __forceinline__ void gll16(const void* g, void* l) {
  __builtin_amdgcn_global_load_lds((gvoid_t*)g, (lvoid_t*)l, 16, 0, 0);
}

__device__ __forceinline__ f32x4 MF(bf16x8 a, bf16x8 b, f32x4 c) {
  return __builtin_amdgcn_mfma_f32_16x16x32_bf16(a, b, c, 0, 0, 0);
}

// raw barrier with compiler memory fence (s_barrier alone is not an opt barrier)
#define BAR() do { asm volatile("" ::: "memory"); __builtin_amdgcn_s_barrier(); asm volatile("" ::: "memory"); } while (0)
#define WAITV8() asm volatile("s_waitcnt vmcnt(8)" ::: "memory")
#define WAITV0() asm volatile("s_waitcnt vmcnt(0)" ::: "memory")
#define WAITL0() asm volatile("s_waitcnt lgkmcnt(0)" ::: "memory")

// ---------------- merged fp32 -> bf16 convert (7 segments, 1 launch) ----------------
struct Cvt7 {
  const float* src[7];
  __bf16* dst[7];
  long off[8];  // prefix sums in float4 units
};
__global__ __launch_bounds__(256) void k_cvt_all(Cvt7 c) {
  long i = (long)blockIdx.x * blockDim.x + threadIdx.x;
  long stride = (long)gridDim.x * blockDim.x;
  long total = c.off[7];
  for (; i < total; i += stride) {
    int seg = 0;
    while (i >= c.off[seg + 1]) ++seg;
    long j = i - c.off[seg];
    float4 v = ((const float4*)c.src[seg])[j];
    bf16x4 o = { (__bf16)v.x, (__bf16)v.y, (__bf16)v.z, (__bf16)v.w };
    ((bf16x4*)c.dst[seg])[j] = o;
  }
}

// ---------------- gate: softmax + biased top-6 ----------------
__global__ __launch_bounds__(256) void k_gate(
    const float* __restrict__ x, const float* __restrict__ gw,
    const float* __restrict__ gb, float* __restrict__ cw,
    int* __restrict__ counts, int* __restrict__ lists,
    int* __restrict__ tok_e, int* __restrict__ tok_pos) {
  int t = blockIdx.x;
  int lane = threadIdx.x & 63, wave = threadIdx.x >> 6;
  __shared__ float sc[NE];
  const float* xt = x + (size_t)t * DD;
  for (int ei = 0; ei < 4; ++ei) {
    int e = wave * 4 + ei;
    const float* ge = gw + (size_t)e * DD;
    float s = 0.f;
    for (int j = 0; j < DD / 64; ++j) s += xt[lane + 64 * j] * ge[lane + 64 * j];
    for (int o = 32; o; o >>= 1) s += __shfl_xor(s, o);
    if (lane == 0) sc[e] = s;
  }
  __syncthreads();
  if (threadIdx.x == 0) {
    float p[NE], b[NE];
    float m = -1e30f;
    for (int e = 0; e < NE; ++e) m = fmaxf(m, sc[e]);
    float sum = 0.f;
    for (int e = 0; e < NE; ++e) { p[e] = expf(sc[e] - m); sum += p[e]; }
    float inv = 1.f / sum;
    for (int e = 0; e < NE; ++e) { p[e] *= inv; b[e] = p[e] + gb[e]; }
    float out[NE];
    bool used[NE];
    for (int e = 0; e < NE; ++e) { out[e] = 0.f; used[e] = false; }
    for (int k = 0; k < TOPK; ++k) {
      int best = -1; float bv = -1e30f;
      for (int e = 0; e < NE; ++e)
        if (!used[e] && b[e] > bv) { bv = b[e]; best = e; }
      used[best] = true;
      out[best] = p[best];  // ROUTE_SCALE = 1.0
      int pos = atomicAdd(&counts[best], 1);
      lists[best * TT + pos] = t;
      tok_e[t * TOPK + k] = best;
      tok_pos[t * TOPK + k] = pos;
    }
    for (int e = 0; e < NE; ++e) cw[(size_t)t * NE + e] = out[e];
  }
}

__global__ void k_offsets(const int* __restrict__ counts, int* __restrict__ offs) {
  if (threadIdx.x == 0) {
    int a = 0;
    for (int e = 0; e < NE; ++e) { offs[e] = a; a += counts[e]; }
    offs[NE] = a;
  }
}

// =====================================================================
// 256x(128+128) fused SwiGLU GEMM1, 512 threads (8 waves = 2m x 4n),
// BK=64, double-buffered LDS (128KB), 8-phase/2-Ktile counted-vmcnt
// schedule, XOR-swizzled LDS (slot ^= row&7) via pre-swizzled global src.
// Derived-waits invariants:
//   - stage region R only after the barrier that retired all reads of R
//     (B* retired at P0-end via WAITL0, A at P1-end).
//   - vmcnt(8) at P3 retires tile k+1's 8 loads (tile k+2's 8 remain).
// =====================================================================
template <bool GATHER>
__global__ __launch_bounds__(512, 1) void k_g1(
    const __bf16* __restrict__ xb,
    const __bf16* __restrict__ W1, const float* __restrict__ B1,
    const __bf16* __restrict__ W3, const float* __restrict__ B3,
    __bf16* __restrict__ Hout, int Hdim,
    const int* __restrict__ counts, const int* __restrict__ offs,
    const int* __restrict__ lists) {
  int e = blockIdx.z;
  int count = GATHER ? counts[e] : TT;
  int m0 = blockIdx.y * 256;
  if (m0 >= count) return;
  int n0 = blockIdx.x * 128;  // col offset within each of W1, W3
  const __bf16* W1e = W1 + (size_t)e * Hdim * DD;
  const __bf16* W3e = W3 + (size_t)e * Hdim * DD;
  const float* B1e = B1 + (size_t)e * Hdim;
  const float* B3e = B3 + (size_t)e * Hdim;
  int hbase = GATHER ? offs[e] : 0;
  const int* liste = GATHER ? lists + (size_t)e * TT : nullptr;

  __shared__ __bf16 At[2][256 * 64];
  __shared__ __bf16 B1t[2][128 * 64];
  __shared__ __bf16 B3t[2][128 * 64];
  __shared__ int rowtok[256];

  int tid = threadIdx.x, lane = tid & 63, w = tid >> 6;
  int wm = w >> 2, wn = w & 3;
  if (tid < 256) {
    int s = m0 + tid;
    rowtok[tid] = GATHER ? liste[s < count ? s : count - 1] : (m0 + tid);
  }
  __syncthreads();

  int l8 = lane >> 3;        // stage: row within 8-row chunk
  int p8 = lane & 7;         // stage: physical 16B slot
  int sw8 = p8 ^ l8;         // stage: logical slot to fetch (row&7 == l8)
  int fr = lane & 15;
  int g4 = lane >> 4;
  int h7 = lane & 7;

  auto stageA = [&](int buf, int kt) {
    int k0 = kt * 64;
    #pragma unroll
    for (int c = 0; c < 4; ++c) {
      int rb = c * 64 + w * 8;
      int tok = rowtok[rb + l8];
      gll16(xb + (size_t)tok * DD + k0 + sw8 * 8, &At[buf][rb * 64]);
    }
  };
  auto stageB = [&](int buf, int kt) {
    int k0 = kt * 64;
    #pragma unroll
    for (int c = 0; c < 2; ++c) {
      int rb = c * 64 + w * 8;
      int r = rb + l8;
      gll16(W1e + (size_t)(n0 + r) * DD + k0 + sw8 * 8, &B1t[buf][rb * 64]);
      gll16(W3e + (size_t)(n0 + r) * DD + k0 + sw8 * 8, &B3t[buf][rb * 64]);
    }
  };

  f32x4 acc1[8][2] = {};
  f32x4 acc3[8][2] = {};

  stageB(0, 0); stageA(0, 0);
  stageB(1, 1); stageA(1, 1);
  WAITV8(); BAR();

  const int nk = DD / 64;
  for (int k = 0; k < nk; ++k) {
    int cur = k & 1;
    bf16x8 a0[8], a1[8], b1f[2][2], b3f[2][2];
    // ---- P0: read all B frags + A kk0 frags ----
    #pragma unroll
    for (int nf = 0; nf < 2; ++nf)
      #pragma unroll
      for (int kk = 0; kk < 2; ++kk) {
        int rr = wn * 32 + nf * 16 + fr;
        int p = (kk * 4 + g4) ^ h7;
        b1f[nf][kk] = *(const bf16x8*)&B1t[cur][rr * 64 + p * 8];
        b3f[nf][kk] = *(const bf16x8*)&B3t[cur][rr * 64 + p * 8];
      }
    #pragma unroll
    for (int mf = 0; mf < 8; ++mf) {
      int rr = wm * 128 + mf * 16 + fr;
      int p = g4 ^ h7;
      a0[mf] = *(const bf16x8*)&At[cur][rr * 64 + p * 8];
    }
    BAR();
    __builtin_amdgcn_s_setprio(1);
    #pragma unroll
    for (int mf = 0; mf < 8; ++mf)
      #pragma unroll
      for (int nf = 0; nf < 2; ++nf)
        acc1[mf][nf] = MF(a0[mf], b1f[nf][0], acc1[mf][nf]);
    __builtin_amdgcn_s_setprio(0);
    WAITL0();  // all P0 reads complete -> B buffers retired
    BAR();
    // ---- P1: read A kk1 frags; stage B(k+2) into retired B buffers ----
    #pragma unroll
    for (int mf = 0; mf < 8; ++mf) {
      int rr = wm * 128 + mf * 16 + fr;
      int p = (4 + g4) ^ h7;
      a1[mf] = *(const bf16x8*)&At[cur][rr * 64 + p * 8];
    }
    if (k + 2 < nk) stageB(cur, k + 2);
    BAR();
    __builtin_amdgcn_s_setprio(1);
    #pragma unroll
    for (int mf = 0; mf < 8; ++mf)
      #pragma unroll
      for (int nf = 0; nf < 2; ++nf)
        acc3[mf][nf] = MF(a0[mf], b3f[nf][0], acc3[mf][nf]);
    __builtin_amdgcn_s_setprio(0);
    WAITL0();  // a1 reads complete -> A buffer retired
    BAR();
    // ---- P2: stage A(k+2) ----
    if (k + 2 < nk) stageA(cur, k + 2);
    BAR();
    __builtin_amdgcn_s_setprio(1);
    #pragma unroll
    for (int mf = 0; mf < 8; ++mf)
      #pragma unroll
      for (int nf = 0; nf < 2; ++nf)
        acc1[mf][nf] = MF(a1[mf], b1f[nf][1], acc1[mf][nf]);
    __builtin_amdgcn_s_setprio(0);
    BAR();
    // ---- P3: counted vmcnt retires tile k+1; never drain in steady state ----
    if (k + 2 < nk) { WAITV8(); }
    else if (k + 1 < nk) { WAITV0(); }
    BAR();
    __builtin_amdgcn_s_setprio(1);
    #pragma unroll
    for (int mf = 0; mf < 8; ++mf)
      #pragma unroll
      for (int nf = 0; nf < 2; ++nf)
        acc3[mf][nf] = MF(a1[mf], b3f[nf][1], acc3[mf][nf]);
    __builtin_amdgcn_s_setprio(0);
    BAR();
  }

  // epilogue: silu(h1+b1)*(h3+b3) -> bf16
  #pragma unroll
  for (int mf = 0; mf < 8; ++mf)
    #pragma unroll
    for (int nf = 0; nf < 2; ++nf)
      #pragma unroll
      for (int j = 0; j < 4; ++j) {
        int rl = wm * 128 + mf * 16 + (lane >> 4) * 4 + j;
        int s = m0 + rl;
        if (s < count) {
          int col = n0 + wn * 32 + nf * 16 + fr;
          float h1 = acc1[mf][nf][j] + B1e[col];
          float h3 = acc3[mf][nf][j] + B3e[col];
          float v = h1 / (1.f + expf(-h1)) * h3;
          Hout[(size_t)(hbase + s) * Hdim + col] = (__bf16)v;
        }
      }
}

// =====================================================================
// 256x256 GEMM2 (h @ W2^T + b2), same 8-phase structure. Routed -> bf16
// Ybuf rows; shared -> fp32 out.
// =====================================================================
template <bool GATHER>
__global__ __launch_bounds__(512, 1) void k_g2(
    const __bf16* __restrict__ Hsrc, int Kd,
    const __bf16* __restrict__ W2, const float* __restrict__ B2,
    float* __restrict__ out, __bf16* __restrict__ Ybuf,
    const int* __restrict__ counts, const int* __restrict__ offs) {
  int e = blockIdx.z;
  int count = GATHER ? counts[e] : TT;
  int m0 = blockIdx.y * 256;
  if (m0 >= count) return;
  int n0 = blockIdx.x * 256;
  int hbase = GATHER ? offs[e] : 0;
  const __bf16* Ae = Hsrc + (size_t)hbase * Kd;
  const __bf16* W2e = W2 + (size_t)e * DD * Kd;
  const float* B2e = B2 + (size_t)(GATHER ? e * DD : 0);

  __shared__ __bf16 At[2][256 * 64];
  __shared__ __bf16 Bt[2][256 * 64];

  int tid = threadIdx.x, lane = tid & 63, w = tid >> 6;
  int wm = w >> 2, wn = w & 3;

  int l8 = lane >> 3;
  int p8 = lane & 7;
  int sw8 = p8 ^ l8;
  int fr = lane & 15;
  int g4 = lane >> 4;
  int h7 = lane & 7;

  auto stageA = [&](int buf, int kt) {
    int k0 = kt * 64;
    #pragma unroll
    for (int c = 0; c < 4; ++c) {
      int rb = c * 64 + w * 8;
      int sr = m0 + rb + l8;
      if (sr >= count) sr = count - 1;
      gll16(Ae + (size_t)sr * Kd + k0 + sw8 * 8, &At[buf][rb * 64]);
    }
  };
  auto stageB = [&](int buf, int kt) {
    int k0 = kt * 64;
    #pragma unroll
    for (int c = 0; c < 4; ++c) {
      int rb = c * 64 + w * 8;
      int r = rb + l8;
      gll16(W2e + (size_t)(n0 + r) * Kd + k0 + sw8 * 8, &Bt[buf][rb * 64]);
    }
  };

  f32x4 acc[8][4] = {};

  stageB(0, 0); stageA(0, 0);
  stageB(1, 1); stageA(1, 1);
  WAITV8(); BAR();

  const int nk = Kd / 64;
  for (int k = 0; k < nk; ++k) {
    int cur = k & 1;
    bf16x8 a0[8], a1[8], bf[4][2];
    // ---- P0: read all B frags + A kk0 ----
    #pragma unroll
    for (int nf = 0; nf < 4; ++nf)
      #pragma unroll
      for (int kk = 0; kk < 2; ++kk) {
        int rr = wn * 64 + nf * 16 + fr;
        int p = (kk * 4 + g4) ^ h7;
        bf[nf][kk] = *(const bf16x8*)&Bt[cur][rr * 64 + p * 8];
      }
    #pragma unroll
    for (int mf = 0; mf < 8; ++mf) {
      int rr = wm * 128 + mf * 16 + fr;
      int p = g4 ^ h7;
      a0[mf] = *(const bf16x8*)&At[cur][rr * 64 + p * 8];
    }
    BAR();
    __builtin_amdgcn_s_setprio(1);
    #pragma unroll
    for (int mf = 0; mf < 8; ++mf)
      #pragma unroll
      for (int nf = 0; nf < 2; ++nf)
        acc[mf][nf] = MF(a0[mf], bf[nf][0], acc[mf][nf]);
    __builtin_amdgcn_s_setprio(0);
    WAITL0();  // B retired
    BAR();
    // ---- P1: read A kk1; stage B(k+2) ----
    #pragma unroll
    for (int mf = 0; mf < 8; ++mf) {
      int rr = wm * 128 + mf * 16 + fr;
      int p = (4 + g4) ^ h7;
      a1[mf] = *(const bf16x8*)&At[cur][rr * 64 + p * 8];
    }
    if (k + 2 < nk) stageB(cur, k + 2);
    BAR();
    __builtin_amdgcn_s_setprio(1);
    #pragma unroll
    for (int mf = 0; mf < 8; ++mf)
      #pragma unroll
      for (int nf = 2; nf < 4; ++nf)
        acc[mf][nf] = MF(a0[mf], bf[nf][0], acc[mf][nf]);
    __builtin_amdgcn_s_setprio(0);
    WAITL0();  // A retired
    BAR();
    // ---- P2: stage A(k+2) ----
    if (k + 2 < nk) stageA(cur, k + 2);
    BAR();
    __builtin_amdgcn_s_setprio(1);
    #pragma unroll
    for (int mf = 0; mf < 8; ++mf)
      #pragma unroll
      for (int nf = 0; nf < 2; ++nf)
        acc[mf][nf] = MF(a1[mf], bf[nf][1], acc[mf][nf]);
    __builtin_amdgcn_s_setprio(0);
    BAR();
    // ---- P3 ----
    if (k + 2 < nk) { WAITV8(); }
    else if (k + 1 < nk) { WAITV0(); }
    BAR();
    __builtin_amdgcn_s_setprio(1);
    #pragma unroll
    for (int mf = 0; mf < 8; ++mf)
      #pragma unroll
      for (int nf = 2; nf < 4; ++nf)
        acc[mf][nf] = MF(a1[mf], bf[nf][1], acc[mf][nf]);
    __builtin_amdgcn_s_setprio(0);
    BAR();
  }

  #pragma unroll
  for (int mf = 0; mf < 8; ++mf)
    #pragma unroll
    for (int nf = 0; nf < 4; ++nf)
      #pragma unroll
      for (int j = 0; j < 4; ++j) {
        int rl = wm * 128 + mf * 16 + (lane >> 4) * 4 + j;
        int s = m0 + rl;
        if (s < count) {
          int d = n0 + wn * 64 + nf * 16 + fr;
          float v = acc[mf][nf][j] + B2e[d];
          if (GATHER)
            Ybuf[(size_t)(hbase + s) * DD + d] = (__bf16)v;
          else
            out[(size_t)s * DD + d] = v;
        }
      }
}

// ---------------- combine: out[t] += sum_k cw * Ybuf[row_k] ----------------
__global__ __launch_bounds__(256) void k_combine(
    const __bf16* __restrict__ Ybuf, const float* __restrict__ cw,
    const int* __restrict__ offs, const int* __restrict__ tok_e,
    const int* __restrict__ tok_pos, float* __restrict__ out) {
  int t = blockIdx.x;
  int tid = threadIdx.x;
  __shared__ int rws[TOPK];
  __shared__ float wsh[TOPK];
  if (tid < TOPK) {
    int e = tok_e[t * TOPK + tid];
    rws[tid] = offs[e] + tok_pos[t * TOPK + tid];
    wsh[tid] = cw[(size_t)t * NE + e];
  }
  __syncthreads();
  int d0 = tid * 8;
  float a[8];
  float4 o0 = *(const float4*)&out[(size_t)t * DD + d0];
  float4 o1 = *(const float4*)&out[(size_t)t * DD + d0 + 4];
  a[0] = o0.x; a[1] = o0.y; a[2] = o0.z; a[3] = o0.w;
  a[4] = o1.x; a[5] = o1.y; a[6] = o1.z; a[7] = o1.w;
  #pragma unroll
  for (int k = 0; k < TOPK; ++k) {
    bf16x8 v = *(const bf16x8*)&Ybuf[(size_t)rws[k] * DD + d0];
    float w = wsh[k];
    #pragma unroll
    for (int j = 0; j < 8; ++j) a[j] += w * (float)v[j];
  }
  float4 r0 = { a[0], a[1], a[2], a[3] };
  float4 r1 = { a[4], a[5], a[6], a[7] };
  *(float4*)&out[(size_t)t * DD + d0] = r0;
  *(float4*)&out[(size_t)t * DD + d0 + 4] = r1;
}

// ---------------- launch ----------------
extern "C" void kernel_launch(void* const* d_in, const int* in_sizes, int n_in,
                              void* d_out, int out_size, void* d_ws, size_t ws_size,
                              hipStream_t stream) {
  const float* x      = (const float*)d_in[0];
  const float* gate_w = (const float*)d_in[1];
  const float* gate_b = (const float*)d_in[2];
  const float* w1     = (const float*)d_in[3];
  const float* b1     = (const float*)d_in[4];
  const float* w2     = (const float*)d_in[5];
  const float* b2     = (const float*)d_in[6];
  const float* w3     = (const float*)d_in[7];
  const float* b3     = (const float*)d_in[8];
  const float* ws1    = (const float*)d_in[9];
  const float* bs1    = (const float*)d_in[10];
  const float* ws2    = (const float*)d_in[11];
  const float* bs2    = (const float*)d_in[12];
  const float* ws3    = (const float*)d_in[13];
  const float* bs3    = (const float*)d_in[14];
  float* outp = (float*)d_out;

  char* ws = (char*)d_ws;
  size_t off = 0;
  auto take = [&](size_t bytes) { char* p = ws + off; off += (bytes + 255) & ~(size_t)255; return p; };
  __bf16* xb   = (__bf16*)take((size_t)TT * DD * 2);
  __bf16* w1b  = (__bf16*)take((size_t)NE * HH * DD * 2);
  __bf16* w3b  = (__bf16*)take((size_t)NE * HH * DD * 2);
  __bf16* w2b  = (__bf16*)take((size_t)NE * DD * HH * 2);
  __bf16* ws1b = (__bf16*)take((size_t)HSH * DD * 2);
  __bf16* ws3b = (__bf16*)take((size_t)HSH * DD * 2);
  __bf16* ws2b = (__bf16*)take((size_t)DD * HSH * 2);
  __bf16* Hbuf = (__bf16*)take((size_t)TT * TOPK * HH * 2);
  __bf16* Sbuf = (__bf16*)take((size_t)TT * HSH * 2);
  float*  cw   = (float*)take((size_t)TT * NE * 4);
  int*    lists  = (int*)take((size_t)NE * TT * 4);
  int*    tok_e  = (int*)take((size_t)TT * TOPK * 4);
  int*    tok_pos= (int*)take((size_t)TT * TOPK * 4);
  int*    counts = (int*)take(64);
  int*    offs   = (int*)take(128);
  // Ybuf (100.7 MB) aliases w1b (115.3 MB): w1b dead after k_g1<true>.
  __bf16* Ybuf = w1b;

  hipMemsetAsync(counts, 0, NE * sizeof(int), stream);

  Cvt7 c;
  const float* srcs[7] = { x, w1, w3, w2, ws1, ws3, ws2 };
  __bf16* dsts[7] = { xb, w1b, w3b, w2b, ws1b, ws3b, ws2b };
  long sz4[7] = { (long)TT * DD / 4, (long)NE * HH * DD / 4, (long)NE * HH * DD / 4,
                  (long)NE * DD * HH / 4, (long)HSH * DD / 4, (long)HSH * DD / 4,
                  (long)DD * HSH / 4 };
  c.off[0] = 0;
  for (int i = 0; i < 7; ++i) { c.src[i] = srcs[i]; c.dst[i] = dsts[i]; c.off[i + 1] = c.off[i] + sz4[i]; }
  k_cvt_all<<<4096, 256, 0, stream>>>(c);

  k_gate<<<TT, 256, 0, stream>>>(x, gate_w, gate_b, cw, counts, lists, tok_e, tok_pos);
  k_offsets<<<1, 64, 0, stream>>>(counts, offs);

  // routed up-proj: 256x(128+128) tiles, 8-phase
  k_g1<true><<<dim3(HH / 128, TT / 256, NE), 512, 0, stream>>>(
      xb, w1b, b1, w3b, b3, Hbuf, HH, counts, offs, lists);
  // shared up-proj
  k_g1<false><<<dim3(HSH / 128, TT / 256, 1), 512, 0, stream>>>(
      xb, ws1b, bs1, ws3b, bs3, Sbuf, HSH, nullptr, nullptr, nullptr);
  // routed down-proj -> Ybuf
  k_g2<true><<<dim3(DD / 256, TT / 256, NE), 512, 0, stream>>>(
      Hbuf, HH, w2b, b2, nullptr, Ybuf, counts, offs);
  // shared down-proj -> out (covers every element)
  k_g2<false><<<dim3(DD / 256, TT / 256, 1), 512, 0, stream>>>(
      Sbuf, HSH, ws2b, bs2, outp, nullptr, nullptr, nullptr);
  // gather-combine routed contributions into out
  k_combine<<<TT, 256, 0, stream>>>(Ybuf, cw, offs, tok_e, tok_pos, outp);
}